// Round 15
// baseline (312.919 us; speedup 1.0000x reference)
//
#include <hip/hip_runtime.h>
#include <stdint.h>

typedef unsigned short u16;
typedef short bf16x8 __attribute__((ext_vector_type(8)));
typedef float f32x4 __attribute__((ext_vector_type(4)));

#define CTX 2048
#define DIN 1024
#define DOUT 1024
#define NB 8

__device__ __forceinline__ u16 f2bf(float f) {
  uint32_t u = __builtin_bit_cast(uint32_t, f);
  u += 0x7FFFu + ((u >> 16) & 1u);
  return (u16)(u >> 16);
}

// global -> LDS async, 16B per lane. LDS dest is wave-uniform base + lane*16.
__device__ __forceinline__ void gld_lds16(const u16* g, const u16* lds) {
  __builtin_amdgcn_global_load_lds(
      (const __attribute__((address_space(1))) uint32_t*)(unsigned long long)(const void*)g,
      (__attribute__((address_space(3))) uint32_t*)(uint32_t)(unsigned long long)(const void*)lds,
      16, 0, 0);
}

#define SBAR() asm volatile("s_barrier" ::: "memory")
#define VMCNT4() asm volatile("s_waitcnt vmcnt(4)" ::: "memory")
#define VMCNT3() asm volatile("s_waitcnt vmcnt(3)" ::: "memory")
#define VMCNT0() asm volatile("s_waitcnt vmcnt(0)" ::: "memory")

// ---------------------------------------------------------------------------
// 256x256-tile GEMM core -- r6 version verbatim (best measured total).
// Rotated schedule, 4 barriers/K-tile, K-loop unrolled x2. vmcnt ledger
// verified r4/r6. Requires nkt even >= 4 (call sites: 16). Single call per
// kernel (no vmcnt follows the epilogue stores).
// ---------------------------------------------------------------------------
template <typename EPI>
__device__ __forceinline__ void gemm256(const u16* __restrict__ A, int lda,
                                        const u16* __restrict__ Bt, int ldb,
                                        int m0, int n0, int K, EPI&& epi) {
  __shared__ __align__(16) u16 lds[65536];  // [buf2][region4][block16][512]

  const int t = threadIdx.x;
  const int lane = t & 63;
  const int w = t >> 6;
  const int wm = w >> 2;
  const int wn = w & 3;
  const int l15 = lane & 15;
  const int l16 = lane >> 4;
  const int nkt = K >> 6;
  const int bf0 = (wn & 1) * 4;

  f32x4 acc[8][4];
#pragma unroll
  for (int i = 0; i < 8; ++i)
#pragma unroll
    for (int j = 0; j < 4; ++j) acc[i][j] = {0.f, 0.f, 0.f, 0.f};

  const u16* gA0 = A + (size_t)(m0 + w * 16 + l15) * lda + l16 * 8;
  const u16* gA1 = gA0 + (size_t)128 * lda;
  const u16* gB0 = Bt + (size_t)(n0 + w * 16 + l15) * ldb + l16 * 8;
  const u16* gB1 = gB0 + (size_t)128 * ldb;

  auto STAGEH = [&](int bb, int rr, const u16* g) {
    u16* d = lds + (((bb * 4 + rr) * 16) + w * 2) * 512;
    gld_lds16(g, d);
    gld_lds16(g + 32, d + 512);
  };

  STAGEH(0, 0, gA0);
  STAGEH(0, 1, gA1);
  STAGEH(0, 2, gB0);
  STAGEH(0, 3, gB1);
  if (nkt > 1) {
    STAGEH(1, 0, gA0 + 64);
    STAGEH(1, 1, gA1 + 64);
  }
  VMCNT4();
  SBAR();

  bf16x8 arLo[4][2], arHi[4][2], br[2][2];

  {
    if (1 < nkt) STAGEH(1, 2, gB0 + 64);
    const u16* bufA = lds + ((0 * 4 + wm) * 16) * 512 + lane * 8;
    const u16* bufB = lds + ((0 * 4 + 2 + (wn >> 1)) * 16) * 512 + lane * 8;
#pragma unroll
    for (int fr = 0; fr < 4; ++fr)
#pragma unroll
      for (int ks = 0; ks < 2; ++ks)
        arLo[fr][ks] = *reinterpret_cast<const bf16x8*>(bufA + (fr * 2 + ks) * 512);
#pragma unroll
    for (int nc = 0; nc < 2; ++nc)
#pragma unroll
      for (int ks = 0; ks < 2; ++ks)
        br[nc][ks] = *reinterpret_cast<const bf16x8*>(bufB + ((bf0 + nc) * 2 + ks) * 512);
    SBAR();
  }

  auto kbody = [&](int T, int b) {
    const u16* bufA = lds + ((b * 4 + wm) * 16) * 512 + lane * 8;
    const u16* bufB = lds + ((b * 4 + 2 + (wn >> 1)) * 16) * 512 + lane * 8;
    const u16* bufAn = lds + (((b ^ 1) * 4 + wm) * 16) * 512 + lane * 8;
    const u16* bufBn = lds + (((b ^ 1) * 4 + 2 + (wn >> 1)) * 16) * 512 + lane * 8;

    if (T + 1 < nkt) STAGEH(b ^ 1, 3, gB1 + (size_t)(T + 1) * 64);
    __builtin_amdgcn_s_setprio(1);
#pragma unroll
    for (int fr = 0; fr < 4; ++fr)
#pragma unroll
      for (int nc = 0; nc < 2; ++nc)
#pragma unroll
        for (int ks = 0; ks < 2; ++ks)
          acc[fr][nc] = __builtin_amdgcn_mfma_f32_16x16x32_bf16(arLo[fr][ks], br[nc][ks],
                                                                acc[fr][nc], 0, 0, 0);
    __builtin_amdgcn_s_setprio(0);
#pragma unroll
    for (int fr = 0; fr < 4; ++fr)
#pragma unroll
      for (int ks = 0; ks < 2; ++ks)
        arHi[fr][ks] = *reinterpret_cast<const bf16x8*>(bufA + ((fr + 4) * 2 + ks) * 512);
    SBAR();

    if (T + 2 < nkt) STAGEH(b, 0, gA0 + (size_t)(T + 2) * 64);
    __builtin_amdgcn_s_setprio(1);
#pragma unroll
    for (int fr = 0; fr < 4; ++fr)
#pragma unroll
      for (int nc = 0; nc < 2; ++nc)
#pragma unroll
        for (int ks = 0; ks < 2; ++ks)
          acc[4 + fr][nc] = __builtin_amdgcn_mfma_f32_16x16x32_bf16(arHi[fr][ks], br[nc][ks],
                                                                    acc[4 + fr][nc], 0, 0, 0);
    __builtin_amdgcn_s_setprio(0);
#pragma unroll
    for (int nc = 0; nc < 2; ++nc)
#pragma unroll
      for (int ks = 0; ks < 2; ++ks)
        br[nc][ks] = *reinterpret_cast<const bf16x8*>(bufB + ((bf0 + 2 + nc) * 2 + ks) * 512);
    SBAR();

    if (T + 2 < nkt) STAGEH(b, 1, gA1 + (size_t)(T + 2) * 64);
    __builtin_amdgcn_s_setprio(1);
#pragma unroll
    for (int fr = 0; fr < 4; ++fr)
#pragma unroll
      for (int nc = 0; nc < 2; ++nc)
#pragma unroll
        for (int ks = 0; ks < 2; ++ks)
          acc[4 + fr][2 + nc] = __builtin_amdgcn_mfma_f32_16x16x32_bf16(arHi[fr][ks], br[nc][ks],
                                                                        acc[4 + fr][2 + nc], 0, 0, 0);
    __builtin_amdgcn_s_setprio(0);
    if (T + 2 < nkt) {
      VMCNT4();
    } else {
      VMCNT0();
    }
    SBAR();

    if (T + 2 < nkt) STAGEH(b, 2, gB0 + (size_t)(T + 2) * 64);
    __builtin_amdgcn_s_setprio(1);
#pragma unroll
    for (int fr = 0; fr < 4; ++fr)
#pragma unroll
      for (int nc = 0; nc < 2; ++nc)
#pragma unroll
        for (int ks = 0; ks < 2; ++ks)
          acc[fr][2 + nc] = __builtin_amdgcn_mfma_f32_16x16x32_bf16(arLo[fr][ks], br[nc][ks],
                                                                    acc[fr][2 + nc], 0, 0, 0);
    __builtin_amdgcn_s_setprio(0);
    if (T + 1 < nkt) {
#pragma unroll
      for (int fr = 0; fr < 4; ++fr)
#pragma unroll
        for (int ks = 0; ks < 2; ++ks)
          arLo[fr][ks] = *reinterpret_cast<const bf16x8*>(bufAn + (fr * 2 + ks) * 512);
#pragma unroll
      for (int nc = 0; nc < 2; ++nc)
#pragma unroll
        for (int ks = 0; ks < 2; ++ks)
          br[nc][ks] = *reinterpret_cast<const bf16x8*>(bufBn + ((bf0 + nc) * 2 + ks) * 512);
    }
    SBAR();
  };

  for (int TT = 0; TT < nkt; TT += 2) {
    kbody(TT, 0);
    kbody(TT + 1, 1);
  }

  epi(acc, wm * 128 + l16 * 4, wn * 64 + l15);
}

// ---------------------------------------------------------------------------
// 128x256-tile GEMM core -- r11 version verbatim (bitwise-verified, VGPR 64,
// no spill, 72 KB LDS -> 2 blocks/CU at launch_bounds(512,4)). BK=32,
// triple-buffered, counted vmcnt(3) ledger. ONE call per kernel here (the
// r13 mixed store/DMA queue hazard is structurally absent).
// ---------------------------------------------------------------------------
template <typename EPI>
__device__ __forceinline__ void gemm128x256(const u16* __restrict__ A, int lda,
                                            const u16* __restrict__ Bt, int ldb,
                                            int m0, int n0, int K, EPI&& epi) {
  __shared__ __align__(16) u16 lds[36864];  // 3 x [A 4096 | B 8192] u16 = 72 KB

  const int t = threadIdx.x;
  const int lane = t & 63;
  const int w = t >> 6;
  const int wm = w >> 2;    // 0..1 (m half: 64 rows)
  const int wn = w & 3;     // 0..3 (n quarter: 64 cols)
  const int l15 = lane & 15;
  const int l16 = lane >> 4;
  const int nkt = K >> 5;   // BK = 32

  f32x4 acc[4][4];
#pragma unroll
  for (int i = 0; i < 4; ++i)
#pragma unroll
    for (int j = 0; j < 4; ++j) acc[i][j] = {0.f, 0.f, 0.f, 0.f};

  const u16* gA = A + (size_t)(m0 + w * 16 + l15) * lda + l16 * 8;
  const u16* gB = Bt + (size_t)(n0 + w * 16 + l15) * ldb + l16 * 8;
  const size_t ldJB = (size_t)128 * ldb;

  auto STAGE = [&](int kbuf, int T) {
    const size_t koff = (size_t)T * 32;
    u16* base = lds + kbuf * 12288;
    gld_lds16(gA + koff, base + w * 512);                 // A rows 0..127
    gld_lds16(gB + koff, base + 4096 + w * 512);          // B rows 0..127
    gld_lds16(gB + koff + ldJB, base + 8192 + w * 512);   // B rows 128..255
  };

  STAGE(0, 0);
  STAGE(1, 1);
  VMCNT3();
  SBAR();

  int cb = 0;
  int sb = 2;
  for (int T = 0; T < nkt; ++T) {
    if (T + 2 < nkt) STAGE(sb, T + 2);

    const u16* bufA = lds + cb * 12288 + (wm * 4) * 512 + lane * 8;
    const u16* bufB = lds + cb * 12288 + 4096 + (wn * 4) * 512 + lane * 8;
    bf16x8 ar[4], br[4];
#pragma unroll
    for (int fr = 0; fr < 4; ++fr)
      ar[fr] = *reinterpret_cast<const bf16x8*>(bufA + fr * 512);
#pragma unroll
    for (int nc = 0; nc < 4; ++nc)
      br[nc] = *reinterpret_cast<const bf16x8*>(bufB + nc * 512);

    __builtin_amdgcn_s_setprio(1);
#pragma unroll
    for (int fr = 0; fr < 4; ++fr)
#pragma unroll
      for (int nc = 0; nc < 4; ++nc)
        acc[fr][nc] = __builtin_amdgcn_mfma_f32_16x16x32_bf16(ar[fr], br[nc],
                                                              acc[fr][nc], 0, 0, 0);
    __builtin_amdgcn_s_setprio(0);
    __builtin_amdgcn_sched_barrier(0);
    if (T + 2 < nkt) {
      VMCNT3();
    } else {
      VMCNT0();
    }
    SBAR();
    cb = (cb == 2) ? 0 : cb + 1;
    sb = (sb == 2) ? 0 : sb + 1;
  }

  epi(acc, wm * 64 + l16 * 4, wn * 64 + l15);
}

// ---------------------------------------------------------------------------
// Merged conversions (one launch): blocks 0..767 transpose Wq|Wk|Wv ->
// Wt_all [3072][1024] bf16; blocks 768.. convert x fp32 -> xb bf16.
__global__ __launch_bounds__(256) void k_cvt_all(const float* __restrict__ x,
                                                 const float* __restrict__ Wq,
                                                 const float* __restrict__ Wk,
                                                 const float* __restrict__ Wv,
                                                 u16* __restrict__ xb,
                                                 u16* __restrict__ Wt_all) {
  __shared__ u16 tile[64][65];
  const int t = threadIdx.x;
  if (blockIdx.x < 768) {
    const int sel = blockIdx.x >> 8;  // 0..2
    const int bc = blockIdx.x & 255;
    const float* W = (sel == 0) ? Wq : ((sel == 1) ? Wk : Wv);
    u16* Wt = Wt_all + ((size_t)sel << 20);
    const int tr0 = (bc >> 4) * 64;
    const int tc0 = (bc & 15) * 64;
    const int col = t & 63, rr = t >> 6;
#pragma unroll
    for (int p = 0; p < 16; ++p) {
      const int row = rr * 16 + p;
      tile[row][col] = f2bf(W[(size_t)(tr0 + row) * DOUT + tc0 + col]);
    }
    __syncthreads();
#pragma unroll
    for (int p = 0; p < 16; ++p) {
      const int row = rr * 16 + p;
      Wt[(size_t)(tc0 + row) * DIN + tr0 + col] = tile[col][row];
    }
  } else {
    const int idx = ((blockIdx.x - 768) * 256 + t) * 4;
    const float4 v = *reinterpret_cast<const float4*>(x + idx);
    ushort4 o;
    o.x = f2bf(v.x); o.y = f2bf(v.y); o.z = f2bf(v.z); o.w = f2bf(v.w);
    *reinterpret_cast<ushort4*>(xb + idx) = o;
  }
}

// Fused QKV projection. 768 blocks, XCD-swizzled; n-tiles 0-7 -> qk row-major,
// 8-11 -> vT transposed.
__global__ __launch_bounds__(512, 2) void k_proj(const u16* __restrict__ xb,
                                                 const u16* __restrict__ Wt,
                                                 u16* __restrict__ qkb,
                                                 u16* __restrict__ vT) {
  const int wg = (blockIdx.x & 7) * 96 + (blockIdx.x >> 3);  // bijective, 768%8==0
  const int m0 = (wg / 12) * 256, n0 = (wg % 12) * 256;
  gemm256(xb, DIN, Wt, DIN, m0, n0, DIN,
          [&](const f32x4(&acc)[8][4], int r0, int c0) {
            if (n0 < 2 * DOUT) {
#pragma unroll
              for (int fr = 0; fr < 8; ++fr)
#pragma unroll
                for (int nc = 0; nc < 4; ++nc) {
                  const int r = m0 + r0 + fr * 16;
                  const int c = n0 + c0 + nc * 16;
#pragma unroll
                  for (int i = 0; i < 4; ++i)
                    qkb[(size_t)(r + i) * 2048 + c] = f2bf(acc[fr][nc][i]);
                }
            } else {
              const int b = m0 >> 11;
              const int sl = (m0 & (CTX - 1)) + r0;
              u16* C = vT + (size_t)b * DOUT * CTX;
#pragma unroll
              for (int fr = 0; fr < 8; ++fr)
#pragma unroll
                for (int nc = 0; nc < 4; ++nc) {
                  const int d = n0 - 2 * DOUT + c0 + nc * 16;
                  const int s = sl + fr * 16;
                  ushort4 o;
                  o.x = f2bf(acc[fr][nc][0]);
                  o.y = f2bf(acc[fr][nc][1]);
                  o.z = f2bf(acc[fr][nc][2]);
                  o.w = f2bf(acc[fr][nc][3]);
                  *reinterpret_cast<ushort4*>(C + (size_t)d * CTX + s) = o;
                }
            }
          });
}

// S[b][i][j] = (q.k)/32, lower-triangular 256x256 tiles (36 per batch)
__global__ __launch_bounds__(512, 2) void k_score(const u16* __restrict__ qkb,
                                                  float* __restrict__ S) {
  const int u = (blockIdx.x & 7) * 36 + (blockIdx.x >> 3);  // 288%8==0
  const int b = u / 36, v = u % 36;
  int it = 0;
  while ((it + 1) * (it + 2) / 2 <= v) ++it;
  const int jt = v - it * (it + 1) / 2;
  const u16* Aq = qkb + (size_t)b * CTX * 2048;
  float* C = S + ((size_t)b << 22);
  const int m0 = it * 256, n0 = jt * 256;
  gemm256(Aq, 2048, Aq + 1024, 2048, m0, n0, DOUT,
          [&](const f32x4(&acc)[8][4], int r0, int c0) {
#pragma unroll
            for (int fr = 0; fr < 8; ++fr)
#pragma unroll
              for (int nc = 0; nc < 4; ++nc) {
                const int r = m0 + r0 + fr * 16;
                const int c = n0 + c0 + nc * 16;
#pragma unroll
                for (int i = 0; i < 4; ++i)
                  C[(size_t)(r + i) * CTX + c] = acc[fr][nc][i] * 0.03125f;
              }
          });
}

// row softmax over S fp32, write P bf16 in place (row stride 4096 u16),
// full 2048 cols written (zeros above diagonal) so PV GEMM needs no masking.
__global__ __launch_bounds__(256) void k_softmax(float* __restrict__ Sws) {
  const int row = blockIdx.x;
  const int b = row >> 11, i = row & (CTX - 1);
  const float* srow = Sws + ((size_t)b << 22) + ((size_t)i << 11);
  u16* prow = (u16*)(Sws + ((size_t)b << 22)) + ((size_t)i << 12);
  const int t = threadIdx.x;
  const int j0 = t * 8;
  float vv[8];
  if (j0 <= i) {
    const float4 v0 = *reinterpret_cast<const float4*>(srow + j0);
    const float4 v1 = *reinterpret_cast<const float4*>(srow + j0 + 4);
    vv[0] = v0.x; vv[1] = v0.y; vv[2] = v0.z; vv[3] = v0.w;
    vv[4] = v1.x; vv[5] = v1.y; vv[6] = v1.z; vv[7] = v1.w;
  } else {
#pragma unroll
    for (int p = 0; p < 8; ++p) vv[p] = -3.0e38f;
  }
  float mx = -3.0e38f;
#pragma unroll
  for (int p = 0; p < 8; ++p) {
    vv[p] = (j0 + p <= i) ? vv[p] : -3.0e38f;
    mx = fmaxf(mx, vv[p]);
  }
#pragma unroll
  for (int off = 32; off > 0; off >>= 1) mx = fmaxf(mx, __shfl_xor(mx, off));
  __shared__ float redm[4], reds[4];
  const int lane = t & 63, wid = t >> 6;
  if (lane == 0) redm[wid] = mx;
  __syncthreads();
  mx = fmaxf(fmaxf(redm[0], redm[1]), fmaxf(redm[2], redm[3]));
  float e[8], s = 0.f;
#pragma unroll
  for (int p = 0; p < 8; ++p) {
    e[p] = __expf(vv[p] - mx);
    s += e[p];
  }
#pragma unroll
  for (int off = 32; off > 0; off >>= 1) s += __shfl_xor(s, off);
  if (lane == 0) reds[wid] = s;
  __syncthreads();  // orders row reads above before in-place writes below
  s = reds[0] + reds[1] + reds[2] + reds[3];
  const float inv = 1.0f / s;
  ushort4 o0, o1;
  o0.x = (j0 + 0 <= i) ? f2bf(e[0] * inv) : (u16)0;
  o0.y = (j0 + 1 <= i) ? f2bf(e[1] * inv) : (u16)0;
  o0.z = (j0 + 2 <= i) ? f2bf(e[2] * inv) : (u16)0;
  o0.w = (j0 + 3 <= i) ? f2bf(e[3] * inv) : (u16)0;
  o1.x = (j0 + 4 <= i) ? f2bf(e[4] * inv) : (u16)0;
  o1.y = (j0 + 5 <= i) ? f2bf(e[5] * inv) : (u16)0;
  o1.z = (j0 + 6 <= i) ? f2bf(e[6] * inv) : (u16)0;
  o1.w = (j0 + 7 <= i) ? f2bf(e[7] * inv) : (u16)0;
  *reinterpret_cast<ushort4*>(prow + j0) = o0;
  *reinterpret_cast<ushort4*>(prow + j0 + 4) = o1;
}

// out[b][i][d] = sum_j P[b][i][j] * V[b][j][d], causal K.
// ROUND-15: r11's single-band form. 512 blocks (16it x 8b x 4nt), LPT
// (longest K first); one gemm128x256 call per block; launch_bounds(512,4)
// with VGPR 64 + 72KB LDS -> 2 co-resident blocks/CU, phase-decorrelated
// (m114 overlap). Load: 4352 K-units / 256 CUs = 17/CU, max job 16 ->
// balanced makespan without the r13 two-call store/DMA hazard.
__global__ __launch_bounds__(512, 4) void k_out(const float* __restrict__ Sws,
                                                const u16* __restrict__ vT,
                                                float* __restrict__ out) {
  const int idx = blockIdx.x;          // 512 = 16it x 8b x 4nt
  const int it = 15 - (idx >> 5);      // longest (K=2048) first
  const int b = (idx >> 2) & 7;
  const int nt = idx & 3;
  const u16* P = (const u16*)(Sws + ((size_t)b << 22));  // lda = 4096 u16
  const u16* Bt = vT + (size_t)b * DOUT * CTX;           // [D][S]
  float* C = out + (size_t)b * CTX * DOUT;
  const int m0 = it * 128, n0 = nt * 256;
  gemm128x256(P, 2 * CTX, Bt, CTX, m0, n0, (it + 1) * 128,
              [&](const f32x4(&acc)[4][4], int r0, int c0) {
#pragma unroll
                for (int fr = 0; fr < 4; ++fr)
#pragma unroll
                  for (int nc = 0; nc < 4; ++nc) {
                    const int r = m0 + r0 + fr * 16;
                    const int c = n0 + c0 + nc * 16;
#pragma unroll
                    for (int i = 0; i < 4; ++i)
                      C[(size_t)(r + i) * DOUT + c] = acc[fr][nc][i];
                  }
              });
}

// ---------------------------------------------------------------------------
extern "C" void kernel_launch(void* const* d_in, const int* in_sizes, int n_in,
                              void* d_out, int out_size, void* d_ws, size_t ws_size,
                              hipStream_t stream) {
  (void)in_sizes; (void)n_in; (void)out_size; (void)ws_size;
  const float* x = (const float*)d_in[0];
  const float* Wq = (const float*)d_in[1];
  const float* Wk = (const float*)d_in[2];
  const float* Wv = (const float*)d_in[3];
  float* out = (float*)d_out;
  uint8_t* ws = (uint8_t*)d_ws;

  // ws layout (224 MB):
  //   [0,128M): S fp32 [8][2048][2048] (P bf16 written in place by softmax)
  //     xb bf16 (32MB) + Wt_all (6MB) overlap S -- dead before k_score runs
  //   [128M,192M): qkb bf16 [8][2048][2048] (q cols 0..1023, k cols 1024..2047)
  //   [192M,224M): vT bf16 [8][1024][2048]
  float* S = (float*)ws;
  u16* xb = (u16*)ws;
  u16* Wt_all = (u16*)(ws + 33554432ull);  // [3072][1024]: q|k|v
  u16* qkb = (u16*)(ws + 134217728ull);
  u16* vT = (u16*)(ws + 201326592ull);

  k_cvt_all<<<768 + 16384, 256, 0, stream>>>(x, Wq, Wk, Wv, xb, Wt_all);
  k_proj<<<768, 512, 0, stream>>>(xb, Wt_all, qkb, vT);
  k_score<<<288, 512, 0, stream>>>(qkb, S);
  k_softmax<<<NB * CTX, 256, 0, stream>>>(S);
  k_out<<<512, 512, 0, stream>>>(S, vT, out);
}

// Round 16
// 292.154 us; speedup vs baseline: 1.0711x; 1.0711x over previous
//
#include <hip/hip_runtime.h>
#include <stdint.h>

typedef unsigned short u16;
typedef short bf16x8 __attribute__((ext_vector_type(8)));
typedef float f32x4 __attribute__((ext_vector_type(4)));

#define CTX 2048
#define DIN 1024
#define DOUT 1024
#define NB 8

__device__ __forceinline__ u16 f2bf(float f) {
  uint32_t u = __builtin_bit_cast(uint32_t, f);
  u += 0x7FFFu + ((u >> 16) & 1u);
  return (u16)(u >> 16);
}

// global -> LDS async, 16B per lane. LDS dest is wave-uniform base + lane*16.
__device__ __forceinline__ void gld_lds16(const u16* g, const u16* lds) {
  __builtin_amdgcn_global_load_lds(
      (const __attribute__((address_space(1))) uint32_t*)(unsigned long long)(const void*)g,
      (__attribute__((address_space(3))) uint32_t*)(uint32_t)(unsigned long long)(const void*)lds,
      16, 0, 0);
}

#define SBAR() asm volatile("s_barrier" ::: "memory")
#define VMCNT4() asm volatile("s_waitcnt vmcnt(4)" ::: "memory")
#define VMCNT3() asm volatile("s_waitcnt vmcnt(3)" ::: "memory")
#define VMCNT0() asm volatile("s_waitcnt vmcnt(0)" ::: "memory")

// ---------------------------------------------------------------------------
// 256x256-tile GEMM core -- r6 version verbatim. Rotated schedule, 4
// barriers/K-tile, K-loop unrolled x2; vmcnt ledger verified r4/r6.
// Requires nkt even >= 4 (call site: 16). Single call per kernel.
// ---------------------------------------------------------------------------
template <typename EPI>
__device__ __forceinline__ void gemm256(const u16* __restrict__ A, int lda,
                                        const u16* __restrict__ Bt, int ldb,
                                        int m0, int n0, int K, EPI&& epi) {
  __shared__ __align__(16) u16 lds[65536];  // [buf2][region4][block16][512]

  const int t = threadIdx.x;
  const int lane = t & 63;
  const int w = t >> 6;
  const int wm = w >> 2;
  const int wn = w & 3;
  const int l15 = lane & 15;
  const int l16 = lane >> 4;
  const int nkt = K >> 6;
  const int bf0 = (wn & 1) * 4;

  f32x4 acc[8][4];
#pragma unroll
  for (int i = 0; i < 8; ++i)
#pragma unroll
    for (int j = 0; j < 4; ++j) acc[i][j] = {0.f, 0.f, 0.f, 0.f};

  const u16* gA0 = A + (size_t)(m0 + w * 16 + l15) * lda + l16 * 8;
  const u16* gA1 = gA0 + (size_t)128 * lda;
  const u16* gB0 = Bt + (size_t)(n0 + w * 16 + l15) * ldb + l16 * 8;
  const u16* gB1 = gB0 + (size_t)128 * ldb;

  auto STAGEH = [&](int bb, int rr, const u16* g) {
    u16* d = lds + (((bb * 4 + rr) * 16) + w * 2) * 512;
    gld_lds16(g, d);
    gld_lds16(g + 32, d + 512);
  };

  STAGEH(0, 0, gA0);
  STAGEH(0, 1, gA1);
  STAGEH(0, 2, gB0);
  STAGEH(0, 3, gB1);
  if (nkt > 1) {
    STAGEH(1, 0, gA0 + 64);
    STAGEH(1, 1, gA1 + 64);
  }
  VMCNT4();
  SBAR();

  bf16x8 arLo[4][2], arHi[4][2], br[2][2];

  {
    if (1 < nkt) STAGEH(1, 2, gB0 + 64);
    const u16* bufA = lds + ((0 * 4 + wm) * 16) * 512 + lane * 8;
    const u16* bufB = lds + ((0 * 4 + 2 + (wn >> 1)) * 16) * 512 + lane * 8;
#pragma unroll
    for (int fr = 0; fr < 4; ++fr)
#pragma unroll
      for (int ks = 0; ks < 2; ++ks)
        arLo[fr][ks] = *reinterpret_cast<const bf16x8*>(bufA + (fr * 2 + ks) * 512);
#pragma unroll
    for (int nc = 0; nc < 2; ++nc)
#pragma unroll
      for (int ks = 0; ks < 2; ++ks)
        br[nc][ks] = *reinterpret_cast<const bf16x8*>(bufB + ((bf0 + nc) * 2 + ks) * 512);
    SBAR();
  }

  auto kbody = [&](int T, int b) {
    const u16* bufA = lds + ((b * 4 + wm) * 16) * 512 + lane * 8;
    const u16* bufB = lds + ((b * 4 + 2 + (wn >> 1)) * 16) * 512 + lane * 8;
    const u16* bufAn = lds + (((b ^ 1) * 4 + wm) * 16) * 512 + lane * 8;
    const u16* bufBn = lds + (((b ^ 1) * 4 + 2 + (wn >> 1)) * 16) * 512 + lane * 8;

    if (T + 1 < nkt) STAGEH(b ^ 1, 3, gB1 + (size_t)(T + 1) * 64);
    __builtin_amdgcn_s_setprio(1);
#pragma unroll
    for (int fr = 0; fr < 4; ++fr)
#pragma unroll
      for (int nc = 0; nc < 2; ++nc)
#pragma unroll
        for (int ks = 0; ks < 2; ++ks)
          acc[fr][nc] = __builtin_amdgcn_mfma_f32_16x16x32_bf16(arLo[fr][ks], br[nc][ks],
                                                                acc[fr][nc], 0, 0, 0);
    __builtin_amdgcn_s_setprio(0);
#pragma unroll
    for (int fr = 0; fr < 4; ++fr)
#pragma unroll
      for (int ks = 0; ks < 2; ++ks)
        arHi[fr][ks] = *reinterpret_cast<const bf16x8*>(bufA + ((fr + 4) * 2 + ks) * 512);
    SBAR();

    if (T + 2 < nkt) STAGEH(b, 0, gA0 + (size_t)(T + 2) * 64);
    __builtin_amdgcn_s_setprio(1);
#pragma unroll
    for (int fr = 0; fr < 4; ++fr)
#pragma unroll
      for (int nc = 0; nc < 2; ++nc)
#pragma unroll
        for (int ks = 0; ks < 2; ++ks)
          acc[4 + fr][nc] = __builtin_amdgcn_mfma_f32_16x16x32_bf16(arHi[fr][ks], br[nc][ks],
                                                                    acc[4 + fr][nc], 0, 0, 0);
    __builtin_amdgcn_s_setprio(0);
#pragma unroll
    for (int nc = 0; nc < 2; ++nc)
#pragma unroll
      for (int ks = 0; ks < 2; ++ks)
        br[nc][ks] = *reinterpret_cast<const bf16x8*>(bufB + ((bf0 + 2 + nc) * 2 + ks) * 512);
    SBAR();

    if (T + 2 < nkt) STAGEH(b, 1, gA1 + (size_t)(T + 2) * 64);
    __builtin_amdgcn_s_setprio(1);
#pragma unroll
    for (int fr = 0; fr < 4; ++fr)
#pragma unroll
      for (int nc = 0; nc < 2; ++nc)
#pragma unroll
        for (int ks = 0; ks < 2; ++ks)
          acc[4 + fr][2 + nc] = __builtin_amdgcn_mfma_f32_16x16x32_bf16(arHi[fr][ks], br[nc][ks],
                                                                        acc[4 + fr][2 + nc], 0, 0, 0);
    __builtin_amdgcn_s_setprio(0);
    if (T + 2 < nkt) {
      VMCNT4();
    } else {
      VMCNT0();
    }
    SBAR();

    if (T + 2 < nkt) STAGEH(b, 2, gB0 + (size_t)(T + 2) * 64);
    __builtin_amdgcn_s_setprio(1);
#pragma unroll
    for (int fr = 0; fr < 4; ++fr)
#pragma unroll
      for (int nc = 0; nc < 2; ++nc)
#pragma unroll
        for (int ks = 0; ks < 2; ++ks)
          acc[fr][2 + nc] = __builtin_amdgcn_mfma_f32_16x16x32_bf16(arLo[fr][ks], br[nc][ks],
                                                                    acc[fr][2 + nc], 0, 0, 0);
    __builtin_amdgcn_s_setprio(0);
    if (T + 1 < nkt) {
#pragma unroll
      for (int fr = 0; fr < 4; ++fr)
#pragma unroll
        for (int ks = 0; ks < 2; ++ks)
          arLo[fr][ks] = *reinterpret_cast<const bf16x8*>(bufAn + (fr * 2 + ks) * 512);
#pragma unroll
      for (int nc = 0; nc < 2; ++nc)
#pragma unroll
        for (int ks = 0; ks < 2; ++ks)
          br[nc][ks] = *reinterpret_cast<const bf16x8*>(bufBn + ((bf0 + nc) * 2 + ks) * 512);
    }
    SBAR();
  };

  for (int TT = 0; TT < nkt; TT += 2) {
    kbody(TT, 0);
    kbody(TT + 1, 1);
  }

  epi(acc, wm * 128 + l16 * 4, wn * 64 + l15);
}

// ---------------------------------------------------------------------------
// 128x256-tile GEMM core -- r11 version verbatim (bitwise-verified, VGPR 64,
// no spill, 72 KB LDS). BK=32, triple-buffered, counted vmcnt(3) ledger.
// Multi-call rule (r14): caller must VMCNT0+SBAR between calls (mixed
// store/DMA vmcnt queue).
// ---------------------------------------------------------------------------
template <typename EPI>
__device__ __forceinline__ void gemm128x256(const u16* __restrict__ A, int lda,
                                            const u16* __restrict__ Bt, int ldb,
                                            int m0, int n0, int K, EPI&& epi) {
  __shared__ __align__(16) u16 lds[36864];  // 3 x [A 4096 | B 8192] u16 = 72 KB

  const int t = threadIdx.x;
  const int lane = t & 63;
  const int w = t >> 6;
  const int wm = w >> 2;    // 0..1 (m half: 64 rows)
  const int wn = w & 3;     // 0..3 (n quarter: 64 cols)
  const int l15 = lane & 15;
  const int l16 = lane >> 4;
  const int nkt = K >> 5;   // BK = 32

  f32x4 acc[4][4];
#pragma unroll
  for (int i = 0; i < 4; ++i)
#pragma unroll
    for (int j = 0; j < 4; ++j) acc[i][j] = {0.f, 0.f, 0.f, 0.f};

  const u16* gA = A + (size_t)(m0 + w * 16 + l15) * lda + l16 * 8;
  const u16* gB = Bt + (size_t)(n0 + w * 16 + l15) * ldb + l16 * 8;
  const size_t ldJB = (size_t)128 * ldb;

  auto STAGE = [&](int kbuf, int T) {
    const size_t koff = (size_t)T * 32;
    u16* base = lds + kbuf * 12288;
    gld_lds16(gA + koff, base + w * 512);                 // A rows 0..127
    gld_lds16(gB + koff, base + 4096 + w * 512);          // B rows 0..127
    gld_lds16(gB + koff + ldJB, base + 8192 + w * 512);   // B rows 128..255
  };

  STAGE(0, 0);
  STAGE(1, 1);
  VMCNT3();
  SBAR();

  int cb = 0;
  int sb = 2;
  for (int T = 0; T < nkt; ++T) {
    if (T + 2 < nkt) STAGE(sb, T + 2);

    const u16* bufA = lds + cb * 12288 + (wm * 4) * 512 + lane * 8;
    const u16* bufB = lds + cb * 12288 + 4096 + (wn * 4) * 512 + lane * 8;
    bf16x8 ar[4], br[4];
#pragma unroll
    for (int fr = 0; fr < 4; ++fr)
      ar[fr] = *reinterpret_cast<const bf16x8*>(bufA + fr * 512);
#pragma unroll
    for (int nc = 0; nc < 4; ++nc)
      br[nc] = *reinterpret_cast<const bf16x8*>(bufB + nc * 512);

    __builtin_amdgcn_s_setprio(1);
#pragma unroll
    for (int fr = 0; fr < 4; ++fr)
#pragma unroll
      for (int nc = 0; nc < 4; ++nc)
        acc[fr][nc] = __builtin_amdgcn_mfma_f32_16x16x32_bf16(ar[fr], br[nc],
                                                              acc[fr][nc], 0, 0, 0);
    __builtin_amdgcn_s_setprio(0);
    __builtin_amdgcn_sched_barrier(0);
    if (T + 2 < nkt) {
      VMCNT3();
    } else {
      VMCNT0();
    }
    SBAR();
    cb = (cb == 2) ? 0 : cb + 1;
    sb = (sb == 2) ? 0 : sb + 1;
  }

  epi(acc, wm * 64 + l16 * 4, wn * 64 + l15);
}

// ---------------------------------------------------------------------------
// Merged conversions (one launch): blocks 0..767 transpose Wq|Wk|Wv ->
// Wt_all [3072][1024] bf16; blocks 768.. convert x fp32 -> xb bf16.
__global__ __launch_bounds__(256) void k_cvt_all(const float* __restrict__ x,
                                                 const float* __restrict__ Wq,
                                                 const float* __restrict__ Wk,
                                                 const float* __restrict__ Wv,
                                                 u16* __restrict__ xb,
                                                 u16* __restrict__ Wt_all) {
  __shared__ u16 tile[64][65];
  const int t = threadIdx.x;
  if (blockIdx.x < 768) {
    const int sel = blockIdx.x >> 8;  // 0..2
    const int bc = blockIdx.x & 255;
    const float* W = (sel == 0) ? Wq : ((sel == 1) ? Wk : Wv);
    u16* Wt = Wt_all + ((size_t)sel << 20);
    const int tr0 = (bc >> 4) * 64;
    const int tc0 = (bc & 15) * 64;
    const int col = t & 63, rr = t >> 6;
#pragma unroll
    for (int p = 0; p < 16; ++p) {
      const int row = rr * 16 + p;
      tile[row][col] = f2bf(W[(size_t)(tr0 + row) * DOUT + tc0 + col]);
    }
    __syncthreads();
#pragma unroll
    for (int p = 0; p < 16; ++p) {
      const int row = rr * 16 + p;
      Wt[(size_t)(tc0 + row) * DIN + tr0 + col] = tile[col][row];
    }
  } else {
    const int idx = ((blockIdx.x - 768) * 256 + t) * 4;
    const float4 v = *reinterpret_cast<const float4*>(x + idx);
    ushort4 o;
    o.x = f2bf(v.x); o.y = f2bf(v.y); o.z = f2bf(v.z); o.w = f2bf(v.w);
    *reinterpret_cast<ushort4*>(xb + idx) = o;
  }
}

// Fused QKV projection. 768 blocks, XCD-swizzled; n-tiles 0-7 -> qk row-major,
// 8-11 -> vT transposed.
__global__ __launch_bounds__(512, 2) void k_proj(const u16* __restrict__ xb,
                                                 const u16* __restrict__ Wt,
                                                 u16* __restrict__ qkb,
                                                 u16* __restrict__ vT) {
  const int wg = (blockIdx.x & 7) * 96 + (blockIdx.x >> 3);  // bijective, 768%8==0
  const int m0 = (wg / 12) * 256, n0 = (wg % 12) * 256;
  gemm256(xb, DIN, Wt, DIN, m0, n0, DIN,
          [&](const f32x4(&acc)[8][4], int r0, int c0) {
            if (n0 < 2 * DOUT) {
#pragma unroll
              for (int fr = 0; fr < 8; ++fr)
#pragma unroll
                for (int nc = 0; nc < 4; ++nc) {
                  const int r = m0 + r0 + fr * 16;
                  const int c = n0 + c0 + nc * 16;
#pragma unroll
                  for (int i = 0; i < 4; ++i)
                    qkb[(size_t)(r + i) * 2048 + c] = f2bf(acc[fr][nc][i]);
                }
            } else {
              const int b = m0 >> 11;
              const int sl = (m0 & (CTX - 1)) + r0;
              u16* C = vT + (size_t)b * DOUT * CTX;
#pragma unroll
              for (int fr = 0; fr < 8; ++fr)
#pragma unroll
                for (int nc = 0; nc < 4; ++nc) {
                  const int d = n0 - 2 * DOUT + c0 + nc * 16;
                  const int s = sl + fr * 16;
                  ushort4 o;
                  o.x = f2bf(acc[fr][nc][0]);
                  o.y = f2bf(acc[fr][nc][1]);
                  o.z = f2bf(acc[fr][nc][2]);
                  o.w = f2bf(acc[fr][nc][3]);
                  *reinterpret_cast<ushort4*>(C + (size_t)d * CTX + s) = o;
                }
            }
          });
}

// S[b][i][j] = (q.k)/32, causal 128x256 tiles (r11's verified mapping):
// it 0..15, jt 0..it/2 -> 72 uniform units/batch x 8 = 576 blocks.
// ROUND-16: replaces the 288x256^2 version whose 288-on-256-CU packing
// serialized a 2nd dispatch round (89us at 62.5% utilization). All units
// uniform -> no r15-style pairing imbalance; makespan ~= 3 half-tile times.
// Diagonal-spanning tiles compute garbage above the diagonal -- softmax
// never reads it (verified passing in r11).
__global__ __launch_bounds__(512, 4) void k_score(const u16* __restrict__ qkb,
                                                  float* __restrict__ S) {
  const int u = (blockIdx.x & 7) * 72 + (blockIdx.x >> 3);  // 576%8==0
  const int b = u / 72, v = u % 72;
  int it = 0, pre = 0;
  while (pre + (it / 2 + 1) <= v) { pre += it / 2 + 1; ++it; }
  const int jt = v - pre;
  const u16* Aq = qkb + (size_t)b * CTX * 2048;
  float* C = S + ((size_t)b << 22);
  const int m0 = it * 128, n0 = jt * 256;
  gemm128x256(Aq, 2048, Aq + 1024, 2048, m0, n0, DOUT,
              [&](const f32x4(&acc)[4][4], int r0, int c0) {
#pragma unroll
                for (int fr = 0; fr < 4; ++fr)
#pragma unroll
                  for (int nc = 0; nc < 4; ++nc) {
                    const int r = m0 + r0 + fr * 16;
                    const int c = n0 + c0 + nc * 16;
#pragma unroll
                    for (int i = 0; i < 4; ++i)
                      C[(size_t)(r + i) * CTX + c] = acc[fr][nc][i] * 0.03125f;
                  }
              });
}

// row softmax over S fp32, write P bf16 in place (row stride 4096 u16),
// full 2048 cols written (zeros above diagonal) so PV GEMM needs no masking.
__global__ __launch_bounds__(256) void k_softmax(float* __restrict__ Sws) {
  const int row = blockIdx.x;
  const int b = row >> 11, i = row & (CTX - 1);
  const float* srow = Sws + ((size_t)b << 22) + ((size_t)i << 11);
  u16* prow = (u16*)(Sws + ((size_t)b << 22)) + ((size_t)i << 12);
  const int t = threadIdx.x;
  const int j0 = t * 8;
  float vv[8];
  if (j0 <= i) {
    const float4 v0 = *reinterpret_cast<const float4*>(srow + j0);
    const float4 v1 = *reinterpret_cast<const float4*>(srow + j0 + 4);
    vv[0] = v0.x; vv[1] = v0.y; vv[2] = v0.z; vv[3] = v0.w;
    vv[4] = v1.x; vv[5] = v1.y; vv[6] = v1.z; vv[7] = v1.w;
  } else {
#pragma unroll
    for (int p = 0; p < 8; ++p) vv[p] = -3.0e38f;
  }
  float mx = -3.0e38f;
#pragma unroll
  for (int p = 0; p < 8; ++p) {
    vv[p] = (j0 + p <= i) ? vv[p] : -3.0e38f;
    mx = fmaxf(mx, vv[p]);
  }
#pragma unroll
  for (int off = 32; off > 0; off >>= 1) mx = fmaxf(mx, __shfl_xor(mx, off));
  __shared__ float redm[4], reds[4];
  const int lane = t & 63, wid = t >> 6;
  if (lane == 0) redm[wid] = mx;
  __syncthreads();
  mx = fmaxf(fmaxf(redm[0], redm[1]), fmaxf(redm[2], redm[3]));
  float e[8], s = 0.f;
#pragma unroll
  for (int p = 0; p < 8; ++p) {
    e[p] = __expf(vv[p] - mx);
    s += e[p];
  }
#pragma unroll
  for (int off = 32; off > 0; off >>= 1) s += __shfl_xor(s, off);
  if (lane == 0) reds[wid] = s;
  __syncthreads();  // orders row reads above before in-place writes below
  s = reds[0] + reds[1] + reds[2] + reds[3];
  const float inv = 1.0f / s;
  ushort4 o0, o1;
  o0.x = (j0 + 0 <= i) ? f2bf(e[0] * inv) : (u16)0;
  o0.y = (j0 + 1 <= i) ? f2bf(e[1] * inv) : (u16)0;
  o0.z = (j0 + 2 <= i) ? f2bf(e[2] * inv) : (u16)0;
  o0.w = (j0 + 3 <= i) ? f2bf(e[3] * inv) : (u16)0;
  o1.x = (j0 + 4 <= i) ? f2bf(e[4] * inv) : (u16)0;
  o1.y = (j0 + 5 <= i) ? f2bf(e[5] * inv) : (u16)0;
  o1.z = (j0 + 6 <= i) ? f2bf(e[6] * inv) : (u16)0;
  o1.w = (j0 + 7 <= i) ? f2bf(e[7] * inv) : (u16)0;
  *reinterpret_cast<ushort4*>(prow + j0) = o0;
  *reinterpret_cast<ushort4*>(prow + j0 + 4) = o1;
}

// out[b][i][d] = sum_j P[b][i][j] * V[b][j][d], causal K.
// r14's uniform folded bands verbatim: 256 blocks (8pp x 8b x 4nt); each
// block runs band it=15-pp then it=pp -- exactly 17 x 128-K per block.
// VMCNT0+SBAR between the calls (r14 store/DMA queue fix).
__global__ __launch_bounds__(512, 4) void k_out(const float* __restrict__ Sws,
                                                const u16* __restrict__ vT,
                                                float* __restrict__ out) {
  const int idx = blockIdx.x;          // 256 = 8pp x 8b x 4nt
  const int pp = idx >> 5;             // 0..7
  const int b = (idx >> 2) & 7;
  const int nt = idx & 3;
  const u16* P = (const u16*)(Sws + ((size_t)b << 22));  // lda = 4096 u16
  const u16* Bt = vT + (size_t)b * DOUT * CTX;           // [D][S]
  float* C = out + (size_t)b * CTX * DOUT;
#pragma unroll 1
  for (int s = 0; s < 2; ++s) {
    const int it = s ? pp : (15 - pp);  // long band first
    const int m0 = it * 128, n0 = nt * 256;
    gemm128x256(P, 2 * CTX, Bt, CTX, m0, n0, (it + 1) * 128,
                [&](const f32x4(&acc)[4][4], int r0, int c0) {
#pragma unroll
                  for (int fr = 0; fr < 4; ++fr)
#pragma unroll
                    for (int nc = 0; nc < 4; ++nc) {
                      const int r = m0 + r0 + fr * 16;
                      const int c = n0 + c0 + nc * 16;
#pragma unroll
                      for (int i = 0; i < 4; ++i)
                        C[(size_t)(r + i) * DOUT + c] = acc[fr][nc][i];
                    }
                });
    VMCNT0();  // drain epilogue stores (+ any DMA) before the next call's
    SBAR();    // counted vmcnt; restores the verified single-call ledger
  }
}

// ---------------------------------------------------------------------------
extern "C" void kernel_launch(void* const* d_in, const int* in_sizes, int n_in,
                              void* d_out, int out_size, void* d_ws, size_t ws_size,
                              hipStream_t stream) {
  (void)in_sizes; (void)n_in; (void)out_size; (void)ws_size;
  const float* x = (const float*)d_in[0];
  const float* Wq = (const float*)d_in[1];
  const float* Wk = (const float*)d_in[2];
  const float* Wv = (const float*)d_in[3];
  float* out = (float*)d_out;
  uint8_t* ws = (uint8_t*)d_ws;

  // ws layout (224 MB):
  //   [0,128M): S fp32 [8][2048][2048] (P bf16 written in place by softmax)
  //     xb bf16 (32MB) + Wt_all (6MB) overlap S -- dead before k_score runs
  //   [128M,192M): qkb bf16 [8][2048][2048] (q cols 0..1023, k cols 1024..2047)
  //   [192M,224M): vT bf16 [8][1024][2048]
  float* S = (float*)ws;
  u16* xb = (u16*)ws;
  u16* Wt_all = (u16*)(ws + 33554432ull);  // [3072][1024]: q|k|v
  u16* qkb = (u16*)(ws + 134217728ull);
  u16* vT = (u16*)(ws + 201326592ull);

  k_cvt_all<<<768 + 16384, 256, 0, stream>>>(x, Wq, Wk, Wv, xb, Wt_all);
  k_proj<<<768, 512, 0, stream>>>(xb, Wt_all, qkb, vT);
  k_score<<<576, 512, 0, stream>>>(qkb, S);
  k_softmax<<<NB * CTX, 256, 0, stream>>>(S);
  k_out<<<256, 512, 0, stream>>>(S, vT, out);
}